// Round 11
// baseline (8367.321 us; speedup 1.0000x reference)
//
#include <hip/hip_runtime.h>

typedef short short8 __attribute__((ext_vector_type(8)));
typedef float f32x4 __attribute__((ext_vector_type(4)));
typedef float f32x16 __attribute__((ext_vector_type(16)));
typedef int i32x4 __attribute__((ext_vector_type(4)));
typedef unsigned short u16;

#define NBLK 128
#define BDIM 512
#define BB 64
#define TT 512
#define II 512
#define HH 1024
#define NCLS 1000
#define HBUF (BB*HH)

__device__ __forceinline__ u16 f2bf(float f) {
  union { float f; unsigned u; } v; v.f = f;
  unsigned u = v.u;
  u += 0x7fffu + ((u >> 16) & 1u);   // RNE
  return (u16)(u >> 16);
}

__device__ __forceinline__ short8 cvt8(f32x4 a, f32x4 b) {
  short8 v;
  v[0] = (short)f2bf(a[0]); v[1] = (short)f2bf(a[1]);
  v[2] = (short)f2bf(a[2]); v[3] = (short)f2bf(a[3]);
  v[4] = (short)f2bf(b[0]); v[5] = (short)f2bf(b[1]);
  v[6] = (short)f2bf(b[2]); v[7] = (short)f2bf(b[3]);
  return v;
}

__device__ __forceinline__ unsigned ld_rlx(const unsigned* p) {
  return __hip_atomic_load(p, __ATOMIC_RELAXED, __HIP_MEMORY_SCOPE_AGENT);
}
__device__ __forceinline__ void st_rlx(unsigned* p, unsigned v) {
  __hip_atomic_store(p, v, __ATOMIC_RELAXED, __HIP_MEMORY_SCOPE_AGENT);
}
// wave-level flag wait: all lanes poll one address (single coalesced request)
__device__ __forceinline__ void wave_wait_ge(const unsigned* p, unsigned tgt) {
  while (ld_rlx(p) < tgt) __builtin_amdgcn_s_sleep(1);
}

// x f32 -> bf16 pre-pass (tier A)
__global__ void cvt_x(const float* __restrict__ x, u16* __restrict__ xb, int n8) {
  int i = blockIdx.x * blockDim.x + threadIdx.x;
  const int stride = gridDim.x * blockDim.x;
  for (; i < n8; i += stride) {
    f32x4 a = ((const f32x4*)x)[2 * i];
    f32x4 b = ((const f32x4*)x)[2 * i + 1];
    ((short8*)xb)[i] = cvt8(a, b);
  }
}

// ---- coherent A-run, 2 M-tiles, 4-frag chunks, 2-deep, counted vmcnt ----
#define ISSUE42(buf, OFF)                                                    \
  _Pragma("unroll") for (int i_ = 0; i_ < 4; ++i_) {                         \
    asm volatile("global_load_dwordx4 %0, %1, off sc0 sc1"                   \
                 : "=v"(buf[2 * i_])     : "v"(lp0 + ((OFF) + i_) * 16));    \
    asm volatile("global_load_dwordx4 %0, %1, off sc0 sc1"                   \
                 : "=v"(buf[2 * i_ + 1]) : "v"(lp1 + ((OFF) + i_) * 16)); }
#define MFMA42(buf, OFF)                                                     \
  _Pragma("unroll") for (int i_ = 0; i_ < 4; ++i_) {                         \
    union { i32x4 q; short8 s; } uA_, uB_;                                   \
    uA_.q = buf[2 * i_]; uB_.q = buf[2 * i_ + 1];                            \
    acc0 = __builtin_amdgcn_mfma_f32_32x32x16_bf16(uA_.s,                    \
             breg[B0 + (OFF) + i_], acc0, 0, 0, 0);                          \
    acc1 = __builtin_amdgcn_mfma_f32_32x32x16_bf16(uB_.s,                    \
             breg[B0 + (OFF) + i_], acc1, 0, 0, 0); }
#define VMWAIT0 asm volatile("s_waitcnt vmcnt(0)" ::: "memory")
#define VMWAIT8 asm volatile("s_waitcnt vmcnt(8)" ::: "memory")
#define SCHEDB  __builtin_amdgcn_sched_barrier(0)

template<int N, int B0, int MH>
__device__ __forceinline__ void run_coh2(const u16* lp0, const u16* lp1,
                                         const short8 (&breg)[MH],
                                         f32x16& acc0, f32x16& acc1) {
  static_assert(N % 4 == 0 && N >= 8, "");
  constexpr int C = N / 4;
  i32x4 bufA[8], bufB[8];
  ISSUE42(bufA, 0);
  ISSUE42(bufB, 4);
#pragma unroll
  for (int c = 0; c < C; ++c) {
    if (c + 2 < C) {
      VMWAIT8; SCHEDB;
      if (c & 1) { MFMA42(bufB, c * 4); ISSUE42(bufB, (c + 2) * 4); }
      else       { MFMA42(bufA, c * 4); ISSUE42(bufA, (c + 2) * 4); }
    } else if (c + 1 < C) {
      VMWAIT8; SCHEDB;
      if (c & 1) { MFMA42(bufB, c * 4); } else { MFMA42(bufA, c * 4); }
    } else {
      VMWAIT0; SCHEDB;
      if (c & 1) { MFMA42(bufB, c * 4); } else { MFMA42(bufA, c * 4); }
    }
  }
}

// plain cached bf16 run, 2 M-tiles (L0 x-section, tier A)
template<int N, int B0, int MH>
__device__ __forceinline__ void run_px2(const u16* lp0, const u16* lp1,
                                        const short8 (&breg)[MH],
                                        f32x16& acc0, f32x16& acc1) {
#pragma unroll
  for (int i = 0; i < N; ++i) {
    short8 a0 = *(const short8*)(lp0 + i * 16);
    short8 a1 = *(const short8*)(lp1 + i * 16);
    acc0 = __builtin_amdgcn_mfma_f32_32x32x16_bf16(a0, breg[B0 + i], acc0, 0, 0, 0);
    acc1 = __builtin_amdgcn_mfma_f32_32x32x16_bf16(a1, breg[B0 + i], acc1, 0, 0, 0);
  }
}

// plain cached f32 run + convert, 2 M-tiles (L0 x-section, tier B)
template<int N, int B0, int MH>
__device__ __forceinline__ void run_pf2(const float* lp0, const float* lp1,
                                        const short8 (&breg)[MH],
                                        f32x16& acc0, f32x16& acc1) {
#pragma unroll
  for (int i = 0; i < N; ++i) {
    short8 a0 = cvt8(*(const f32x4*)(lp0 + i * 16), *(const f32x4*)(lp0 + i * 16 + 4));
    short8 a1 = cvt8(*(const f32x4*)(lp1 + i * 16), *(const f32x4*)(lp1 + i * 16 + 4));
    acc0 = __builtin_amdgcn_mfma_f32_32x32x16_bf16(a0, breg[B0 + i], acc0, 0, 0, 0);
    acc1 = __builtin_amdgcn_mfma_f32_32x32x16_bf16(a1, breg[B0 + i], acc1, 0, 0, 0);
  }
}

// Decoupled persistent 2-layer LSTM, 64-blocks-per-layer edition.
// Blocks [0,64)=L0, [64,128)=L1; each block owns 16 hidden units (64 gate rows).
// 8 waves = 2 gate-row-groups x 4 K-quarters, 2 M-tile accumulators per wave.
// Weights gathered ONCE from global f32 into registers (no LDS staging).
// Halves the per-step LLC h broadcast (64 readers instead of 128 per layer).
template<bool XBF>
__global__ __launch_bounds__(BDIM, 2) void lstm2_fused(
    const float* __restrict__ x, const u16* __restrict__ xb,
    const float* __restrict__ Wih0, const float* __restrict__ Whh0,
    const float* __restrict__ bih0, const float* __restrict__ bhh0,
    const float* __restrict__ Wih1, const float* __restrict__ Whh1,
    const float* __restrict__ bih1, const float* __restrict__ bhh1,
    u16* __restrict__ ring,          // 3 x [64][1024] bf16 (h0)
    u16* __restrict__ h1buf,         // 2 x [64][1024] bf16 (h1)
    float* __restrict__ h1f,
    unsigned* __restrict__ bar)
{
  __shared__ float g4[4][64][65];        // 65 KB K-partial buffer (padded col)
  __shared__ float blds[64];             // fused biases (64 gate rows)

  const bool isL1 = (blockIdx.x >= 64);
  const int wgl = isL1 ? (int)blockIdx.x - 64 : (int)blockIdx.x;
  const int j0 = wgl * 16;               // first hidden unit owned

  const int lane = threadIdx.x & 63;
  const int wid = threadIdx.x >> 6;      // 8 waves
  const int gr = wid & 1, kq = wid >> 1; // 2 row-groups x 4 K-quarters
  const int sub8 = (lane >> 5) << 3;     // k sub-offset within 16-k fragment
  const int rl = gr * 32 + (lane & 31);  // gate-row local [0,64)
  const int rglob = ((rl >> 4) << 10) + j0 + (rl & 15);  // gate*1024 + unit

  // biases
  if (threadIdx.x < 64) {
    int u = threadIdx.x;
    int r = ((u >> 4) << 10) + j0 + (u & 15);
    blds[u] = isL1 ? (bih1[r] + bhh1[r]) : (bih0[r] + bhh0[r]);
  }
  __syncthreads();

  const int tb = threadIdx.x >> 3;       // tail batch row
  const int uu = (threadIdx.x & 7) << 1; // tail: 2 units per thread

  unsigned* const arrA = bar;            // L0 arrive
  unsigned* const relA = bar + 64;       // "h0(t) visible" <=> relA >= t+1
  unsigned* const arrB = bar + 128;      // L1 arrive
  unsigned* const relB = bar + 192;      // "h1(t) visible" <=> relB >= t+1

  float cst0 = 0.f, cst1 = 0.f;

  // tail: combine 4 K-partials, gates, c/h update, coherent h store, arrive
  auto step_tail = [&](const f32x16& acc0, const f32x16& acc1, u16* hout,
                       unsigned ringtgt, bool wf, unsigned* arr, unsigned* rel,
                       int t) {
#pragma unroll
    for (int r = 0; r < 16; ++r) {
      int brow = (r & 3) + ((r >> 2) << 3) + ((lane >> 5) << 2);
      g4[kq][brow][rl] = acc0[r];
      g4[kq][brow + 32][rl] = acc1[r];
    }
    __syncthreads();
    float hva, hvb;
    {
      float gi = g4[0][tb][uu] + g4[1][tb][uu] + g4[2][tb][uu] + g4[3][tb][uu] + blds[uu];
      float gf = g4[0][tb][16+uu] + g4[1][tb][16+uu] + g4[2][tb][16+uu] + g4[3][tb][16+uu] + blds[16+uu];
      float gg = g4[0][tb][32+uu] + g4[1][tb][32+uu] + g4[2][tb][32+uu] + g4[3][tb][32+uu] + blds[32+uu];
      float go = g4[0][tb][48+uu] + g4[1][tb][48+uu] + g4[2][tb][48+uu] + g4[3][tb][48+uu] + blds[48+uu];
      gi = 1.f / (1.f + __expf(-gi));
      gf = 1.f / (1.f + __expf(-gf));
      go = 1.f / (1.f + __expf(-go));
      float e2 = __expf(2.f * fminf(15.f, fmaxf(-15.f, gg)));
      gg = (e2 - 1.f) / (e2 + 1.f);
      cst0 = gf * cst0 + gi * gg;
      float e2c = __expf(2.f * fminf(15.f, fmaxf(-15.f, cst0)));
      hva = go * (e2c - 1.f) / (e2c + 1.f);
    }
    {
      int u1 = uu + 1;
      float gi = g4[0][tb][u1] + g4[1][tb][u1] + g4[2][tb][u1] + g4[3][tb][u1] + blds[u1];
      float gf = g4[0][tb][16+u1] + g4[1][tb][16+u1] + g4[2][tb][16+u1] + g4[3][tb][16+u1] + blds[16+u1];
      float gg = g4[0][tb][32+u1] + g4[1][tb][32+u1] + g4[2][tb][32+u1] + g4[3][tb][32+u1] + blds[32+u1];
      float go = g4[0][tb][48+u1] + g4[1][tb][48+u1] + g4[2][tb][48+u1] + g4[3][tb][48+u1] + blds[48+u1];
      gi = 1.f / (1.f + __expf(-gi));
      gf = 1.f / (1.f + __expf(-gf));
      go = 1.f / (1.f + __expf(-go));
      float e2 = __expf(2.f * fminf(15.f, fmaxf(-15.f, gg)));
      gg = (e2 - 1.f) / (e2 + 1.f);
      cst1 = gf * cst1 + gi * gg;
      float e2c = __expf(2.f * fminf(15.f, fmaxf(-15.f, cst1)));
      hvb = go * (e2c - 1.f) / (e2c + 1.f);
    }
    if (ringtgt) wave_wait_ge(relB, ringtgt);     // L0 ring slot reuse guard
    unsigned packed = (unsigned)f2bf(hva) | ((unsigned)f2bf(hvb) << 16);
    st_rlx((unsigned*)(hout + (size_t)tb * HH + j0 + uu), packed);
    if (wf) {
      h1f[(size_t)tb * HH + j0 + uu] = hva;
      h1f[(size_t)tb * HH + j0 + uu + 1] = hvb;
    }
    __syncthreads();                    // drains h stores; g4 reads done
    if (threadIdx.x == 0) {             // arrive; 64th poster releases. NO wait.
      unsigned old = atomicAdd(arr, 1u);
      if (old == (unsigned)(64 * (t + 1) - 1)) st_rlx(rel, (unsigned)(t + 1));
    }
  };

  if (!isL1) {
    // ======= layer 0: 24 frags/wave (K=1536: x 512 + h0 1024) ================
    short8 breg[24];
#pragma unroll
    for (int i = 0; i < 24; ++i) {
      int k = kq * 384 + i * 16 + sub8;
      const float* src = (k < II) ? (Wih0 + (size_t)rglob * II + k)
                                  : (Whh0 + (size_t)rglob * HH + (k - II));
      breg[i] = cvt8(*(const f32x4*)src, *(const f32x4*)(src + 4));
    }

    for (int t = 0; t < TT; ++t) {
      f32x16 acc0 = {}, acc1 = {};
      const u16* hb = ring + (size_t)((t + 2) % 3) * HBUF
                      + (size_t)(lane & 31) * HH;
      const u16* hb1 = hb + (size_t)32 * HH;
      if (XBF) {
        const u16* xl0 = xb + (size_t)(lane & 31) * ((size_t)TT * II)
                         + (size_t)t * II + kq * 384 + sub8;
        const u16* xl1 = xl0 + (size_t)32 * TT * II;
        if (kq == 0)      run_px2<24, 0>(xl0, xl1, breg, acc0, acc1);
        else if (kq == 1) { run_px2<8, 0>(xl0, xl1, breg, acc0, acc1);
                            wave_wait_ge(relA, (unsigned)t);
                            run_coh2<16, 8>(hb + sub8, hb1 + sub8, breg, acc0, acc1); }
        else if (kq == 2) { wave_wait_ge(relA, (unsigned)t);
                            run_coh2<24, 0>(hb + 256 + sub8, hb1 + 256 + sub8, breg, acc0, acc1); }
        else              { wave_wait_ge(relA, (unsigned)t);
                            run_coh2<24, 0>(hb + 640 + sub8, hb1 + 640 + sub8, breg, acc0, acc1); }
      } else {
        const float* xl0 = x + (size_t)(lane & 31) * ((size_t)TT * II)
                           + (size_t)t * II + kq * 384 + sub8;
        const float* xl1 = xl0 + (size_t)32 * TT * II;
        if (kq == 0)      run_pf2<24, 0>(xl0, xl1, breg, acc0, acc1);
        else if (kq == 1) { run_pf2<8, 0>(xl0, xl1, breg, acc0, acc1);
                            wave_wait_ge(relA, (unsigned)t);
                            run_coh2<16, 8>(hb + sub8, hb1 + sub8, breg, acc0, acc1); }
        else if (kq == 2) { wave_wait_ge(relA, (unsigned)t);
                            run_coh2<24, 0>(hb + 256 + sub8, hb1 + 256 + sub8, breg, acc0, acc1); }
        else              { wave_wait_ge(relA, (unsigned)t);
                            run_coh2<24, 0>(hb + 640 + sub8, hb1 + 640 + sub8, breg, acc0, acc1); }
      }
      step_tail(acc0, acc1, ring + (size_t)(t % 3) * HBUF,
                (t >= 3) ? (unsigned)(t - 2) : 0u, false, arrA, relA, t);
    }
  } else {
    // ======= layer 1: 32 frags/wave (K=2048: h0 1024 + h1 1024) ==============
    short8 breg[32];
#pragma unroll
    for (int i = 0; i < 32; ++i) {
      int k = kq * 512 + i * 16 + sub8;
      const float* src = (k < HH) ? (Wih1 + (size_t)rglob * HH + k)
                                  : (Whh1 + (size_t)rglob * HH + (k - HH));
      breg[i] = cvt8(*(const f32x4*)src, *(const f32x4*)(src + 4));
    }

    for (int t = 0; t < TT; ++t) {
      f32x16 acc0 = {}, acc1 = {};
      if (kq < 2) {                      // input: h0(t) = ring slot t%3
        wave_wait_ge(relA, (unsigned)(t + 1));
        const u16* lp0 = ring + (size_t)(t % 3) * HBUF
                         + (size_t)(lane & 31) * HH + kq * 512 + sub8;
        const u16* lp1 = lp0 + (size_t)32 * HH;
        run_coh2<32, 0>(lp0, lp1, breg, acc0, acc1);
      } else {                           // recurrent: h1(t-1)
        wave_wait_ge(relB, (unsigned)t);
        const u16* lp0 = h1buf + (size_t)((t + 1) & 1) * HBUF
                         + (size_t)(lane & 31) * HH + (kq - 2) * 512 + sub8;
        const u16* lp1 = lp0 + (size_t)32 * HH;
        run_coh2<32, 0>(lp0, lp1, breg, acc0, acc1);
      }
      step_tail(acc0, acc1, h1buf + (size_t)(t & 1) * HBUF, 0u, t == TT - 1,
                arrB, relB, t);
    }
  }
}

// out[b][c] = sum_k h1f[b][k] * Wd[c][k] + bd[c]   (all f32)
__global__ void dense_out(const float* __restrict__ h1, const float* __restrict__ Wd,
                          const float* __restrict__ bd, float* __restrict__ out)
{
  const int b  = threadIdx.x & 63;
  const int cl = threadIdx.x >> 6;
  const int cc = blockIdx.x * 4 + cl;    // class (250*4 = 1000)
  float acc = 0.f;
  const float* hrow = h1 + (size_t)b * HH;
  const float* wrow = Wd + (size_t)cc * HH;
#pragma unroll 8
  for (int k = 0; k < HH; k += 4) {
    f32x4 hv = *(const f32x4*)(hrow + k);
    f32x4 wv = *(const f32x4*)(wrow + k);
    acc += hv[0] * wv[0] + hv[1] * wv[1] + hv[2] * wv[2] + hv[3] * wv[3];
  }
  out[(size_t)b * NCLS + cc] = acc + bd[cc];
}

extern "C" void kernel_launch(void* const* d_in, const int* in_sizes, int n_in,
                              void* d_out, int out_size, void* d_ws, size_t ws_size,
                              hipStream_t stream)
{
  (void)in_sizes; (void)n_in; (void)out_size;
  const float* x    = (const float*)d_in[0];
  const float* Wih0 = (const float*)d_in[1];
  const float* Whh0 = (const float*)d_in[2];
  const float* bih0 = (const float*)d_in[3];
  const float* bhh0 = (const float*)d_in[4];
  const float* Wih1 = (const float*)d_in[5];
  const float* Whh1 = (const float*)d_in[6];
  const float* bih1 = (const float*)d_in[7];
  const float* bhh1 = (const float*)d_in[8];
  const float* Wd   = (const float*)d_in[9];
  const float* bd   = (const float*)d_in[10];

  unsigned* bar = (unsigned*)d_ws;                       // 4 KB flag/counter lines
  float* h1f  = (float*)((char*)d_ws + 4096);            // 256 KB
  u16* h1buf  = (u16*)((char*)d_ws + 272 * 1024);        // 2 x 128 KB
  u16* ring   = (u16*)((char*)d_ws + 528 * 1024);        // 3 x 128 KB
  u16* xb     = (u16*)((char*)d_ws + (1u << 20));        // 33.6 MB (tier A)

  const size_t needA = (1u << 20) + (size_t)BB * TT * II * 2;
  const bool tierA = (ws_size >= needA);

  // zero flags + h buffers every launch (graph-replay deterministic)
  hipMemsetAsync(d_ws, 0, 912 * 1024, stream);

  if (tierA) {
    hipLaunchKernelGGL(cvt_x, dim3(2048), dim3(256), 0, stream,
                       x, xb, (int)((size_t)BB * TT * II / 8));
    hipLaunchKernelGGL((lstm2_fused<true>), dim3(NBLK), dim3(BDIM), 0, stream,
                       x, xb, Wih0, Whh0, bih0, bhh0, Wih1, Whh1, bih1, bhh1,
                       ring, h1buf, h1f, bar);
  } else {
    hipLaunchKernelGGL((lstm2_fused<false>), dim3(NBLK), dim3(BDIM), 0, stream,
                       x, xb, Wih0, Whh0, bih0, bhh0, Wih1, Whh1, bih1, bhh1,
                       ring, h1buf, h1f, bar);
  }
  hipLaunchKernelGGL(dense_out, dim3(250), dim3(256), 0, stream, h1f, Wd, bd,
                     (float*)d_out);
}

// Round 12
// 4669.313 us; speedup vs baseline: 1.7920x; 1.7920x over previous
//
#include <hip/hip_runtime.h>

typedef short short8 __attribute__((ext_vector_type(8)));
typedef float f32x4 __attribute__((ext_vector_type(4)));
typedef float f32x16 __attribute__((ext_vector_type(16)));
typedef int i32x4 __attribute__((ext_vector_type(4)));
typedef unsigned short u16;

#define NBLK 256
#define BDIM 512
#define BB 64
#define TT 512
#define II 512
#define HH 1024
#define NCLS 1000
#define HBUF (BB*HH)

__device__ __forceinline__ u16 f2bf(float f) {
  union { float f; unsigned u; } v; v.f = f;
  unsigned u = v.u;
  u += 0x7fffu + ((u >> 16) & 1u);   // RNE
  return (u16)(u >> 16);
}

__device__ __forceinline__ short8 cvt8(f32x4 a, f32x4 b) {
  short8 v;
  v[0] = (short)f2bf(a[0]); v[1] = (short)f2bf(a[1]);
  v[2] = (short)f2bf(a[2]); v[3] = (short)f2bf(a[3]);
  v[4] = (short)f2bf(b[0]); v[5] = (short)f2bf(b[1]);
  v[6] = (short)f2bf(b[2]); v[7] = (short)f2bf(b[3]);
  return v;
}

__device__ __forceinline__ unsigned ld_rlx(const unsigned* p) {
  return __hip_atomic_load(p, __ATOMIC_RELAXED, __HIP_MEMORY_SCOPE_AGENT);
}
__device__ __forceinline__ void st_rlx(unsigned* p, unsigned v) {
  __hip_atomic_store(p, v, __ATOMIC_RELAXED, __HIP_MEMORY_SCOPE_AGENT);
}
// wave-level flag wait: all lanes poll one address (single coalesced request)
__device__ __forceinline__ void wave_wait_ge(const unsigned* p, unsigned tgt) {
  while (ld_rlx(p) < tgt) __builtin_amdgcn_s_sleep(1);
}

// x f32 -> bf16 pre-pass (tier A)
__global__ void cvt_x(const float* __restrict__ x, u16* __restrict__ xb, int n8) {
  int i = blockIdx.x * blockDim.x + threadIdx.x;
  const int stride = gridDim.x * blockDim.x;
  for (; i < n8; i += stride) {
    f32x4 a = ((const f32x4*)x)[2 * i];
    f32x4 b = ((const f32x4*)x)[2 * i + 1];
    ((short8*)xb)[i] = cvt8(a, b);
  }
}

// ---- coherent fragment run: 2-deep pipelined batches, counted vmcnt (R9) ----
#define ISSUE8(arr, OFF)                                                     \
  _Pragma("unroll") for (int i_ = 0; i_ < 8; ++i_)                           \
    asm volatile("global_load_dwordx4 %0, %1, off sc0 sc1"                   \
                 : "=v"(arr[i_]) : "v"(lanep + ((OFF) + i_) * 16));
#define MFMA8(arr, OFF)                                                      \
  _Pragma("unroll") for (int i_ = 0; i_ < 8; ++i_) {                         \
    union { i32x4 q; short8 s; } u_; u_.q = arr[i_];                         \
    acc = __builtin_amdgcn_mfma_f32_32x32x16_bf16(u_.s, breg[B0 + (OFF) + i_],\
                                                  acc, 0, 0, 0); }
#define VMWAIT0 asm volatile("s_waitcnt vmcnt(0)" ::: "memory")
#define VMWAIT8 asm volatile("s_waitcnt vmcnt(8)" ::: "memory")
#define SCHEDB  __builtin_amdgcn_sched_barrier(0)

template<int N, int B0, int MH>
__device__ __forceinline__ void run_coh(const u16* lanep,
                                        const short8 (&breg)[MH], f32x16& acc) {
  static_assert(N == 8 || N == 16 || N == 24 || N == 32, "");
  i32x4 avA[8], avB[8];
  if constexpr (N == 8) {
    ISSUE8(avA, 0);
    VMWAIT0; SCHEDB; MFMA8(avA, 0);
  } else if constexpr (N == 16) {
    ISSUE8(avA, 0); ISSUE8(avB, 8);
    VMWAIT8; SCHEDB; MFMA8(avA, 0);
    VMWAIT0; SCHEDB; MFMA8(avB, 8);
  } else if constexpr (N == 24) {
    ISSUE8(avA, 0); ISSUE8(avB, 8);
    VMWAIT8; SCHEDB; MFMA8(avA, 0); ISSUE8(avA, 16);
    VMWAIT8; SCHEDB; MFMA8(avB, 8);
    VMWAIT0; SCHEDB; MFMA8(avA, 16);
  } else {
    ISSUE8(avA, 0); ISSUE8(avB, 8);
    VMWAIT8; SCHEDB; MFMA8(avA, 0); ISSUE8(avA, 16);
    VMWAIT8; SCHEDB; MFMA8(avB, 8); ISSUE8(avB, 24);
    VMWAIT8; SCHEDB; MFMA8(avA, 16);
    VMWAIT0; SCHEDB; MFMA8(avB, 24);
  }
}

// plain cached bf16 run (L0 x-section, tier A)
template<int N, int B0, int MH>
__device__ __forceinline__ void run_pb(const u16* lanep,
                                       const short8 (&breg)[MH], f32x16& acc) {
#pragma unroll
  for (int i = 0; i < N; ++i) {
    short8 av = *(const short8*)(lanep + i * 16);
    acc = __builtin_amdgcn_mfma_f32_32x32x16_bf16(av, breg[B0 + i], acc, 0, 0, 0);
  }
}

// plain cached f32 run + convert (L0 x-section, tier B)
template<int N, int B0, int MH>
__device__ __forceinline__ void run_pf(const float* lanep,
                                       const short8 (&breg)[MH], f32x16& acc) {
#pragma unroll
  for (int i = 0; i < N; ++i) {
    short8 av = cvt8(*(const f32x4*)(lanep + i * 16),
                     *(const f32x4*)(lanep + i * 16 + 4));
    acc = __builtin_amdgcn_mfma_f32_32x32x16_bf16(av, breg[B0 + i], acc, 0, 0, 0);
  }
}

// Decoupled persistent 2-layer LSTM, batch-split edition.
// Blocks [0,128)=L0, [128,256)=L1. Per layer: 64 unit-groups x 2 batch-halves;
// a block owns 16 units (64 gate rows) x 32 batch rows. 8 waves = 2 gate-row-
// groups x 4 K-quarters; per-wave shape identical to R9 (breg[32]/[24], one
// f32x16 acc, 2-deep pipelined coherent A loads) but each block reads only its
// 32 batch rows of h -> per-stage coherent LLC traffic halves (48 -> 24 MB).
// Weights gathered once from global f32 into registers; LDS is only g4+bias.
template<bool XBF>
__global__ __launch_bounds__(BDIM, 2) void lstm2_fused(
    const float* __restrict__ x, const u16* __restrict__ xb,
    const float* __restrict__ Wih0, const float* __restrict__ Whh0,
    const float* __restrict__ bih0, const float* __restrict__ bhh0,
    const float* __restrict__ Wih1, const float* __restrict__ Whh1,
    const float* __restrict__ bih1, const float* __restrict__ bhh1,
    u16* __restrict__ ring,          // 3 x [64][1024] bf16 (h0)
    u16* __restrict__ h1buf,         // 2 x [64][1024] bf16 (h1)
    float* __restrict__ h1f,
    unsigned* __restrict__ bar)
{
  __shared__ float g4[4][32][68];        // 34.8 KB K-partial buffer (padded)
  __shared__ float blds[64];             // fused biases (64 gate rows)

  const bool isL1 = (blockIdx.x >= 128);
  const int wgl = isL1 ? (int)blockIdx.x - 128 : (int)blockIdx.x;
  const int ug = wgl >> 1, bg = wgl & 1;
  const int j0 = ug * 16;                // first hidden unit owned
  const int rowoff = bg * 32;            // first batch row owned

  const int lane = threadIdx.x & 63;
  const int wid = threadIdx.x >> 6;      // 8 waves
  const int gr = wid & 1, kq = wid >> 1; // 2 gate-row-groups x 4 K-quarters
  const int sub8 = (lane >> 5) << 3;     // k sub-offset within 16-k fragment
  const int rl = gr * 32 + (lane & 31);  // gate-row local [0,64) = gate*16+unit
  const int rglob = ((rl >> 4) << 10) + j0 + (rl & 15);
  const int arow = rowoff + (lane & 31); // A (batch) row this lane loads

  if (threadIdx.x < 64) {                // biases
    int u = threadIdx.x;
    int r = ((u >> 4) << 10) + j0 + (u & 15);
    blds[u] = isL1 ? (bih1[r] + bhh1[r]) : (bih0[r] + bhh0[r]);
  }
  __syncthreads();

  const int tb = threadIdx.x >> 4;       // tail batch row local [0,32)
  const int tu = threadIdx.x & 15;       // tail unit [0,16)

  unsigned* const arrA = bar;            // L0 arrive
  unsigned* const relA = bar + 64;       // "h0(t) visible" <=> relA >= t+1
  unsigned* const arrB = bar + 128;      // L1 arrive
  unsigned* const relB = bar + 192;      // "h1(t) visible" <=> relB >= t+1

  float c_state = 0.f;

  // tail: combine 4 K-partials, gates, c/h update, coherent h store, arrive
  auto step_tail = [&](const f32x16& acc, u16* hout, unsigned ringtgt, bool wf,
                       unsigned* arr, unsigned* rel, int t) {
    const int col = lane & 31;
    const int rbase = (lane >> 5) << 2;
#pragma unroll
    for (int r = 0; r < 16; ++r) {
      int brow = rbase + (r & 3) + ((r >> 2) << 3);   // C/D row (batch, [0,32))
      g4[kq][brow][gr * 32 + col] = acc[r];
    }
    __syncthreads();
    float gv[4];
#pragma unroll
    for (int g = 0; g < 4; ++g)
      gv[g] = g4[0][tb][g * 16 + tu] + g4[1][tb][g * 16 + tu]
            + g4[2][tb][g * 16 + tu] + g4[3][tb][g * 16 + tu]
            + blds[g * 16 + tu];
    float gi = 1.f / (1.f + __expf(-gv[0]));
    float gf = 1.f / (1.f + __expf(-gv[1]));
    float e2 = __expf(2.f * fminf(15.f, fmaxf(-15.f, gv[2])));
    float gg = (e2 - 1.f) / (e2 + 1.f);
    float go = 1.f / (1.f + __expf(-gv[3]));
    c_state = gf * c_state + gi * gg;
    float e2c = __expf(2.f * fminf(15.f, fmaxf(-15.f, c_state)));
    float th = (e2c - 1.f) / (e2c + 1.f);
    float hval = go * th;
    if (ringtgt) wave_wait_ge(relB, ringtgt);   // L0 ring slot reuse guard
    unsigned hu = (unsigned)f2bf(hval);
    unsigned nbv = (unsigned)__shfl_xor((int)hu, 1);
    if ((tu & 1) == 0) {
      unsigned packed = hu | (nbv << 16);
      unsigned* dst = (unsigned*)(hout + (size_t)(rowoff + tb) * HH + j0 + tu);
      st_rlx(dst, packed);
    }
    if (wf) h1f[(size_t)(rowoff + tb) * HH + j0 + tu] = hval;
    __syncthreads();                    // drains h stores before arrive
    if (threadIdx.x == 0) {             // arrive; 128th poster releases. NO wait.
      unsigned old = atomicAdd(arr, 1u);
      if (old == (unsigned)(128 * (t + 1) - 1)) st_rlx(rel, (unsigned)(t + 1));
    }
  };

  if (!isL1) {
    // ======= layer 0: K=1536 (x 512 | h0 1024), 24 frags/wave ================
    short8 breg[24];
#pragma unroll
    for (int i = 0; i < 24; ++i) {
      int k = kq * 384 + i * 16 + sub8;
      const float* src = (k < II) ? (Wih0 + (size_t)rglob * II + k)
                                  : (Whh0 + (size_t)rglob * HH + (k - II));
      breg[i] = cvt8(*(const f32x4*)src, *(const f32x4*)(src + 4));
    }

    for (int t = 0; t < TT; ++t) {
      f32x16 acc = {};
      const u16* hb = ring + (size_t)((t + 2) % 3) * HBUF + (size_t)arow * HH;
      if (XBF) {
        const u16* xl = xb + (size_t)arow * ((size_t)TT * II) + (size_t)t * II
                        + kq * 384 + sub8;
        if (kq == 0)      run_pb<24, 0>(xl, breg, acc);
        else if (kq == 1) { run_pb<8, 0>(xl, breg, acc);
                            wave_wait_ge(relA, (unsigned)t);
                            run_coh<16, 8>(hb + 0 + sub8, breg, acc); }
        else if (kq == 2) { wave_wait_ge(relA, (unsigned)t);
                            run_coh<24, 0>(hb + 256 + sub8, breg, acc); }
        else              { wave_wait_ge(relA, (unsigned)t);
                            run_coh<24, 0>(hb + 640 + sub8, breg, acc); }
      } else {
        const float* xl = x + (size_t)arow * ((size_t)TT * II) + (size_t)t * II
                          + kq * 384 + sub8;
        if (kq == 0)      run_pf<24, 0>(xl, breg, acc);
        else if (kq == 1) { run_pf<8, 0>(xl, breg, acc);
                            wave_wait_ge(relA, (unsigned)t);
                            run_coh<16, 8>(hb + 0 + sub8, breg, acc); }
        else if (kq == 2) { wave_wait_ge(relA, (unsigned)t);
                            run_coh<24, 0>(hb + 256 + sub8, breg, acc); }
        else              { wave_wait_ge(relA, (unsigned)t);
                            run_coh<24, 0>(hb + 640 + sub8, breg, acc); }
      }
      step_tail(acc, ring + (size_t)(t % 3) * HBUF,
                (t >= 3) ? (unsigned)(t - 2) : 0u, false, arrA, relA, t);
    }
  } else {
    // ======= layer 1: K=2048 (h0 1024 | h1 1024), 32 frags/wave ==============
    short8 breg[32];
#pragma unroll
    for (int i = 0; i < 32; ++i) {
      int k = kq * 512 + i * 16 + sub8;
      const float* src = (k < HH) ? (Wih1 + (size_t)rglob * HH + k)
                                  : (Whh1 + (size_t)rglob * HH + (k - HH));
      breg[i] = cvt8(*(const f32x4*)src, *(const f32x4*)(src + 4));
    }

    for (int t = 0; t < TT; ++t) {
      f32x16 acc = {};
      if (kq < 2) {                      // input: h0(t) = ring slot t%3
        wave_wait_ge(relA, (unsigned)(t + 1));
        const u16* lp = ring + (size_t)(t % 3) * HBUF + (size_t)arow * HH
                        + kq * 512 + sub8;
        run_coh<32, 0>(lp, breg, acc);
      } else {                           // recurrent: h1(t-1)
        wave_wait_ge(relB, (unsigned)t);
        const u16* lp = h1buf + (size_t)((t + 1) & 1) * HBUF
                        + (size_t)arow * HH + (kq - 2) * 512 + sub8;
        run_coh<32, 0>(lp, breg, acc);
      }
      step_tail(acc, h1buf + (size_t)(t & 1) * HBUF, 0u, t == TT - 1,
                arrB, relB, t);
    }
  }
}

// out[b][c] = sum_k h1f[b][k] * Wd[c][k] + bd[c]   (all f32)
__global__ void dense_out(const float* __restrict__ h1, const float* __restrict__ Wd,
                          const float* __restrict__ bd, float* __restrict__ out)
{
  const int b  = threadIdx.x & 63;
  const int cl = threadIdx.x >> 6;
  const int cc = blockIdx.x * 4 + cl;    // class (250*4 = 1000)
  float acc = 0.f;
  const float* hrow = h1 + (size_t)b * HH;
  const float* wrow = Wd + (size_t)cc * HH;
#pragma unroll 8
  for (int k = 0; k < HH; k += 4) {
    f32x4 hv = *(const f32x4*)(hrow + k);
    f32x4 wv = *(const f32x4*)(wrow + k);
    acc += hv[0] * wv[0] + hv[1] * wv[1] + hv[2] * wv[2] + hv[3] * wv[3];
  }
  out[(size_t)b * NCLS + cc] = acc + bd[cc];
}

extern "C" void kernel_launch(void* const* d_in, const int* in_sizes, int n_in,
                              void* d_out, int out_size, void* d_ws, size_t ws_size,
                              hipStream_t stream)
{
  (void)in_sizes; (void)n_in; (void)out_size;
  const float* x    = (const float*)d_in[0];
  const float* Wih0 = (const float*)d_in[1];
  const float* Whh0 = (const float*)d_in[2];
  const float* bih0 = (const float*)d_in[3];
  const float* bhh0 = (const float*)d_in[4];
  const float* Wih1 = (const float*)d_in[5];
  const float* Whh1 = (const float*)d_in[6];
  const float* bih1 = (const float*)d_in[7];
  const float* bhh1 = (const float*)d_in[8];
  const float* Wd   = (const float*)d_in[9];
  const float* bd   = (const float*)d_in[10];

  unsigned* bar = (unsigned*)d_ws;                       // 4 KB flag/counter lines
  float* h1f  = (float*)((char*)d_ws + 4096);            // 256 KB
  u16* h1buf  = (u16*)((char*)d_ws + 272 * 1024);        // 2 x 128 KB
  u16* ring   = (u16*)((char*)d_ws + 528 * 1024);        // 3 x 128 KB
  u16* xb     = (u16*)((char*)d_ws + (1u << 20));        // 33.6 MB (tier A)

  const size_t needA = (1u << 20) + (size_t)BB * TT * II * 2;
  const bool tierA = (ws_size >= needA);

  // zero flags + h buffers every launch (graph-replay deterministic)
  hipMemsetAsync(d_ws, 0, 912 * 1024, stream);

  if (tierA) {
    hipLaunchKernelGGL(cvt_x, dim3(2048), dim3(256), 0, stream,
                       x, xb, (int)((size_t)BB * TT * II / 8));
    hipLaunchKernelGGL((lstm2_fused<true>), dim3(NBLK), dim3(BDIM), 0, stream,
                       x, xb, Wih0, Whh0, bih0, bhh0, Wih1, Whh1, bih1, bhh1,
                       ring, h1buf, h1f, bar);
  } else {
    hipLaunchKernelGGL((lstm2_fused<false>), dim3(NBLK), dim3(BDIM), 0, stream,
                       x, xb, Wih0, Whh0, bih0, bhh0, Wih1, Whh1, bih1, bhh1,
                       ring, h1buf, h1f, bar);
  }
  hipLaunchKernelGGL(dense_out, dim3(250), dim3(256), 0, stream, h1f, Wd, bd,
                     (float*)d_out);
}